// Round 1
// baseline (738.101 us; speedup 1.0000x reference)
//
#include <hip/hip_runtime.h>

#define NN 50000
#define EE 800000
#define NEG 0.2f

typedef long long i64;

static __device__ __forceinline__ float wave_max64(float v) {
#pragma unroll
  for (int m = 32; m >= 1; m >>= 1) v = fmaxf(v, __shfl_xor(v, m, 64));
  return v;
}
static __device__ __forceinline__ float wave_sum64(float v) {
#pragma unroll
  for (int m = 32; m >= 1; m >>= 1) v += __shfl_xor(v, m, 64);
  return v;
}

// ---- edge_index dtype probe: int64 vs int32 ------------------------------
__global__ void k_detect(const void* ei, int* flag) {
  if (blockIdx.x == 0 && threadIdx.x == 0) {
    const i64* p = (const i64*)ei;
    int ok = 1;
    for (int k = 0; k < 256; ++k) {
      i64 v = p[k];
      if (v < 0 || v >= NN) { ok = 0; break; }
    }
    *flag = ok;  // 1 => data really is int64
  }
}

static __device__ __forceinline__ int edge_at(const void* ei, int is64, int idx) {
  return is64 ? (int)((const i64*)ei)[idx] : ((const int*)ei)[idx];
}

// ---- CSR build (by destination) ------------------------------------------
__global__ void k_zero(int* deg, int* cur) {
  int i = blockIdx.x * blockDim.x + threadIdx.x;
  if (i < NN) { deg[i] = 0; cur[i] = 0; }
}

__global__ void k_count(const void* ei, const int* flag, int* deg) {
  int e = blockIdx.x * blockDim.x + threadIdx.x;
  if (e >= EE) return;
  int is64 = *flag;
  atomicAdd(&deg[edge_at(ei, is64, EE + e)], 1);
}

__global__ void k_dinv(const int* deg, float* dinv) {
  int i = blockIdx.x * blockDim.x + threadIdx.x;
  if (i < NN) dinv[i] = rsqrtf((float)(deg[i] + 1));  // +1 = self loop
}

__global__ void k_scan1(const int* deg, int* rowp, int* bsums) {
  __shared__ int sh[256];
  int t = threadIdx.x;
  int base = blockIdx.x * 1024 + t * 4;
  int v[4]; int s = 0;
#pragma unroll
  for (int j = 0; j < 4; ++j) { int idx = base + j; int x = (idx < NN) ? deg[idx] : 0; v[j] = x; s += x; }
  sh[t] = s; __syncthreads();
  for (int off = 1; off < 256; off <<= 1) {
    int x = (t >= off) ? sh[t - off] : 0;
    __syncthreads();
    sh[t] += x;
    __syncthreads();
  }
  if (t == 255) bsums[blockIdx.x] = sh[255];
  int run = sh[t] - s;  // exclusive prefix of this thread's chunk
#pragma unroll
  for (int j = 0; j < 4; ++j) { int idx = base + j; if (idx < NN) rowp[idx] = run; run += v[j]; }
}

__global__ void k_scan2(int* bsums, int* rowp, int nb) {
  if (blockIdx.x == 0 && threadIdx.x == 0) {
    int acc = 0;
    for (int i = 0; i < nb; ++i) { int v = bsums[i]; bsums[i] = acc; acc += v; }
    rowp[NN] = acc;  // == EE
  }
}

__global__ void k_scan3(int* rowp, const int* bsums) {
  int i = blockIdx.x * blockDim.x + threadIdx.x;
  if (i < NN) rowp[i] += bsums[i >> 10];
}

__global__ void k_fill(const void* ei, const int* flag, const int* rowp, int* cur, int* csr) {
  int e = blockIdx.x * blockDim.x + threadIdx.x;
  if (e >= EE) return;
  int is64 = *flag;
  int s = edge_at(ei, is64, e);
  int d = edge_at(ei, is64, EE + e);
  int pos = rowp[d] + atomicAdd(&cur[d], 1);
  csr[pos] = s;
}

// ---- dense GEMM: Y[n][OC] = X[n][K] @ W[K][OC], W staged in LDS ----------
template <int K, int OC, int ROWS>
__global__ void k_gemm(const float* __restrict__ X, const float* __restrict__ W,
                       float* __restrict__ Y, int n) {
  __shared__ float Wl[K * OC];
  int t = threadIdx.x;
  for (int i = t; i < K * OC; i += 256) Wl[i] = W[i];
  __syncthreads();
  int col = t % OC;
  int r0 = t / OC;
  const int NR = 256 / OC;
  int rowBase = blockIdx.x * ROWS;
  for (int r = r0; r < ROWS; r += NR) {
    int row = rowBase + r;
    if (row >= n) break;
    const float* xr = X + (size_t)row * K;
    float acc = 0.f;
#pragma unroll 8
    for (int k = 0; k < K; ++k) acc += xr[k] * Wl[k * OC + col];
    Y[(size_t)row * OC + col] = acc;
  }
}

// ---- GCN aggregation: wave per node, lane = feature (64) -----------------
__global__ void k_gcn(const float* __restrict__ g, const float* __restrict__ dinv,
                      const int* __restrict__ rowp, const int* __restrict__ csr,
                      const float* __restrict__ bias, float* __restrict__ out) {
  int wid = (blockIdx.x * blockDim.x + threadIdx.x) >> 6;
  int lane = threadIdx.x & 63;
  if (wid >= NN) return;
  float di = dinv[wid];
  float acc = g[(size_t)wid * 64 + lane] * di;  // self loop (norm = di*di)
  int beg = rowp[wid], end = rowp[wid + 1];
  for (int e = beg; e < end; ++e) {
    int s = csr[e];
    acc += g[(size_t)s * 64 + lane] * dinv[s];
  }
  float v = acc * di + bias[lane];
  out[(size_t)wid * 64 + lane] = fmaxf(v, 0.f);
}

// ---- attention coefficients ----------------------------------------------
// GAT1: hg [N][128] (H=2,C=64), weights [2][64] flat 128
__global__ void k_att1(const float* __restrict__ hg, const float* __restrict__ aw_s,
                       const float* __restrict__ aw_d, float* __restrict__ a_s,
                       float* __restrict__ a_d) {
  int wid = (blockIdx.x * blockDim.x + threadIdx.x) >> 6;
  int lane = threadIdx.x & 63;
  if (wid >= NN) return;
  const float* h = hg + (size_t)wid * 128;
  float h0 = h[lane], h1 = h[lane + 64];
  float s0 = wave_sum64(h0 * aw_s[lane]);
  float s1 = wave_sum64(h1 * aw_s[lane + 64]);
  float d0 = wave_sum64(h0 * aw_d[lane]);
  float d1 = wave_sum64(h1 * aw_d[lane + 64]);
  if (lane == 0) {
    a_s[wid * 2] = s0; a_s[wid * 2 + 1] = s1;
    a_d[wid * 2] = d0; a_d[wid * 2 + 1] = d1;
  }
}

// GAT2: hg [N][64] (H=2,C=32), weights [2][32] flat 64
__global__ void k_att2(const float* __restrict__ hg, const float* __restrict__ aw_s,
                       const float* __restrict__ aw_d, float* __restrict__ a_s,
                       float* __restrict__ a_d) {
  int wid = (blockIdx.x * blockDim.x + threadIdx.x) >> 6;
  int lane = threadIdx.x & 63;
  if (wid >= NN) return;
  float h0 = hg[(size_t)wid * 64 + lane];
  float s = h0 * aw_s[lane];
  float d = h0 * aw_d[lane];
#pragma unroll
  for (int m = 16; m >= 1; m >>= 1) { s += __shfl_xor(s, m, 64); d += __shfl_xor(d, m, 64); }
  if ((lane & 31) == 0) {
    a_s[wid * 2 + (lane >> 5)] = s;
    a_d[wid * 2 + (lane >> 5)] = d;
  }
}

// ---- GAT layer 1 aggregation (H=2, C=64, concat, relu) -------------------
__global__ void k_gat1(const float* __restrict__ hg, const float* __restrict__ a_s,
                       const float* __restrict__ a_d, const int* __restrict__ rowp,
                       const int* __restrict__ csr, const float* __restrict__ bias,
                       float* __restrict__ out) {
  int wid = (blockIdx.x * blockDim.x + threadIdx.x) >> 6;
  int lane = threadIdx.x & 63;
  if (wid >= NN) return;
  int beg = rowp[wid];
  int cnt = rowp[wid + 1] - beg;  // real edges; +1 self loop handled below
  float ad0 = a_d[wid * 2], ad1 = a_d[wid * 2 + 1];

  float m0 = -1e30f, m1 = -1e30f;
  for (int idx = lane; idx < cnt + 1; idx += 64) {
    int s = (idx < cnt) ? csr[beg + idx] : wid;
    float e0 = a_s[s * 2] + ad0, e1 = a_s[s * 2 + 1] + ad1;
    e0 = e0 > 0.f ? e0 : NEG * e0;
    e1 = e1 > 0.f ? e1 : NEG * e1;
    m0 = fmaxf(m0, e0); m1 = fmaxf(m1, e1);
  }
  m0 = wave_max64(m0); m1 = wave_max64(m1);

  float s0 = 0.f, s1 = 0.f;
  for (int idx = lane; idx < cnt + 1; idx += 64) {
    int s = (idx < cnt) ? csr[beg + idx] : wid;
    float e0 = a_s[s * 2] + ad0, e1 = a_s[s * 2 + 1] + ad1;
    e0 = e0 > 0.f ? e0 : NEG * e0;
    e1 = e1 > 0.f ? e1 : NEG * e1;
    s0 += __expf(e0 - m0); s1 += __expf(e1 - m1);
  }
  s0 = wave_sum64(s0); s1 = wave_sum64(s1);
  float inv0 = 1.f / s0, inv1 = 1.f / s1;

  float acc0 = 0.f, acc1 = 0.f;
  for (int idx = 0; idx < cnt + 1; ++idx) {
    int s = (idx < cnt) ? csr[beg + idx] : wid;
    float e0 = a_s[s * 2] + ad0, e1 = a_s[s * 2 + 1] + ad1;
    e0 = e0 > 0.f ? e0 : NEG * e0;
    e1 = e1 > 0.f ? e1 : NEG * e1;
    float al0 = __expf(e0 - m0) * inv0;
    float al1 = __expf(e1 - m1) * inv1;
    acc0 += hg[(size_t)s * 128 + lane] * al0;
    acc1 += hg[(size_t)s * 128 + 64 + lane] * al1;
  }
  out[(size_t)wid * 128 + lane]      = fmaxf(acc0 + bias[lane], 0.f);
  out[(size_t)wid * 128 + 64 + lane] = fmaxf(acc1 + bias[64 + lane], 0.f);
}

// ---- GAT layer 2 aggregation (H=2, C=32, head-mean) + log_softmax --------
__global__ void k_gat2(const float* __restrict__ hg, const float* __restrict__ a_s,
                       const float* __restrict__ a_d, const int* __restrict__ rowp,
                       const int* __restrict__ csr, const float* __restrict__ bias,
                       float* __restrict__ out) {
  int wid = (blockIdx.x * blockDim.x + threadIdx.x) >> 6;
  int lane = threadIdx.x & 63;
  if (wid >= NN) return;
  int hh = lane >> 5, c = lane & 31;
  int beg = rowp[wid];
  int cnt = rowp[wid + 1] - beg;
  float ad0 = a_d[wid * 2], ad1 = a_d[wid * 2 + 1];
  float adh = hh ? ad1 : ad0;

  float m0 = -1e30f, m1 = -1e30f;
  for (int idx = lane; idx < cnt + 1; idx += 64) {
    int s = (idx < cnt) ? csr[beg + idx] : wid;
    float e0 = a_s[s * 2] + ad0, e1 = a_s[s * 2 + 1] + ad1;
    e0 = e0 > 0.f ? e0 : NEG * e0;
    e1 = e1 > 0.f ? e1 : NEG * e1;
    m0 = fmaxf(m0, e0); m1 = fmaxf(m1, e1);
  }
  m0 = wave_max64(m0); m1 = wave_max64(m1);

  float s0 = 0.f, s1 = 0.f;
  for (int idx = lane; idx < cnt + 1; idx += 64) {
    int s = (idx < cnt) ? csr[beg + idx] : wid;
    float e0 = a_s[s * 2] + ad0, e1 = a_s[s * 2 + 1] + ad1;
    e0 = e0 > 0.f ? e0 : NEG * e0;
    e1 = e1 > 0.f ? e1 : NEG * e1;
    s0 += __expf(e0 - m0); s1 += __expf(e1 - m1);
  }
  s0 = wave_sum64(s0); s1 = wave_sum64(s1);
  float mh = hh ? m1 : m0;
  float invh = 1.f / (hh ? s1 : s0);

  float acc = 0.f;
  for (int idx = 0; idx < cnt + 1; ++idx) {
    int s = (idx < cnt) ? csr[beg + idx] : wid;
    float e = a_s[s * 2 + hh] + adh;
    e = e > 0.f ? e : NEG * e;
    acc += hg[(size_t)s * 64 + lane] * (__expf(e - mh) * invh);
  }
  // mean over heads: partner lane (^32) holds the other head, same c
  float v = 0.5f * (acc + __shfl_xor(acc, 32, 64)) + bias[c];
  // log_softmax over the 32 classes (within each 32-lane half)
  float mx = v;
#pragma unroll
  for (int m = 16; m >= 1; m >>= 1) mx = fmaxf(mx, __shfl_xor(mx, m, 64));
  float se = __expf(v - mx);
#pragma unroll
  for (int m = 16; m >= 1; m >>= 1) se += __shfl_xor(se, m, 64);
  float o = v - mx - __logf(se);
  if (lane < 32) out[(size_t)wid * 32 + c] = o;
}

// --------------------------------------------------------------------------
extern "C" void kernel_launch(void* const* d_in, const int* in_sizes, int n_in,
                              void* d_out, int out_size, void* d_ws, size_t ws_size,
                              hipStream_t stream) {
  (void)in_sizes; (void)n_in; (void)out_size; (void)ws_size;
  const float* x   = (const float*)d_in[0];
  const void*  ei  = d_in[1];
  const float* W1  = (const float*)d_in[2];
  const float* b1  = (const float*)d_in[3];
  const float* W2  = (const float*)d_in[4];
  const float* b2  = (const float*)d_in[5];
  const float* Wg1 = (const float*)d_in[6];
  const float* as1 = (const float*)d_in[7];
  const float* ad1 = (const float*)d_in[8];
  const float* bg1 = (const float*)d_in[9];
  const float* Wg2 = (const float*)d_in[10];
  const float* as2 = (const float*)d_in[11];
  const float* ad2 = (const float*)d_in[12];
  const float* bg2 = (const float*)d_in[13];
  float* out = (float*)d_out;

  char* w = (char*)d_ws;
  auto alloc = [&](size_t bytes) { char* p = w; w += (bytes + 255) & ~(size_t)255; return p; };
  float* B1   = (float*)alloc((size_t)NN * 128 * 4);
  float* B2   = (float*)alloc((size_t)NN * 128 * 4);
  float* dinv = (float*)alloc((size_t)NN * 4);
  float* asb  = (float*)alloc((size_t)NN * 2 * 4);
  float* adb  = (float*)alloc((size_t)NN * 2 * 4);
  int* deg    = (int*)alloc((size_t)NN * 4);
  int* rowp   = (int*)alloc((size_t)(NN + 1) * 4);
  int* cur    = (int*)alloc((size_t)NN * 4);
  int* csr    = (int*)alloc((size_t)EE * 4);
  int* bsums  = (int*)alloc(64 * 4);
  int* flag   = (int*)alloc(16);

  const int TB = 256;
  int gN = (NN + TB - 1) / TB;      // node-parallel, thread per node
  int gE = (EE + TB - 1) / TB;      // edge-parallel
  int gW = (NN + 3) / 4;            // wave per node, 4 waves/block
  int nScan = (NN + 1023) / 1024;   // 49

  k_detect<<<1, 64, 0, stream>>>(ei, flag);
  k_zero<<<gN, TB, 0, stream>>>(deg, cur);
  k_count<<<gE, TB, 0, stream>>>(ei, flag, deg);
  k_dinv<<<gN, TB, 0, stream>>>(deg, dinv);
  k_scan1<<<nScan, TB, 0, stream>>>(deg, rowp, bsums);
  k_scan2<<<1, 64, 0, stream>>>(bsums, rowp, nScan);
  k_scan3<<<gN, TB, 0, stream>>>(rowp, bsums);
  k_fill<<<gE, TB, 0, stream>>>(ei, flag, rowp, cur, csr);

  // GCN 1: x@W1 -> agg -> relu
  k_gemm<128, 64, 64><<<(NN + 63) / 64, TB, 0, stream>>>(x, W1, B1, NN);
  k_gcn<<<gW, TB, 0, stream>>>(B1, dinv, rowp, csr, b1, B2);
  // GCN 2
  k_gemm<64, 64, 64><<<(NN + 63) / 64, TB, 0, stream>>>(B2, W2, B1, NN);
  k_gcn<<<gW, TB, 0, stream>>>(B1, dinv, rowp, csr, b2, B2);
  // GAT 1 (concat, relu)
  k_gemm<64, 128, 64><<<(NN + 63) / 64, TB, 0, stream>>>(B2, Wg1, B1, NN);
  k_att1<<<gW, TB, 0, stream>>>(B1, as1, ad1, asb, adb);
  k_gat1<<<gW, TB, 0, stream>>>(B1, asb, adb, rowp, csr, bg1, B2);
  // GAT 2 (head mean) + log_softmax
  k_gemm<128, 64, 64><<<(NN + 63) / 64, TB, 0, stream>>>(B2, Wg2, B1, NN);
  k_att2<<<gW, TB, 0, stream>>>(B1, as2, ad2, asb, adb);
  k_gat2<<<gW, TB, 0, stream>>>(B1, asb, adb, rowp, csr, bg2, out);
}

// Round 2
// 457.841 us; speedup vs baseline: 1.6121x; 1.6121x over previous
//
#include <hip/hip_runtime.h>

#define NN 50000
#define EE 800000
#define NEG 0.2f
#define CAP 128   // per-wave LDS edge stash capacity (deg ~Poisson(16); fallback path kept)

typedef long long i64;

static __device__ __forceinline__ float wave_max64(float v) {
#pragma unroll
  for (int m = 32; m >= 1; m >>= 1) v = fmaxf(v, __shfl_xor(v, m, 64));
  return v;
}
static __device__ __forceinline__ float wave_sum64(float v) {
#pragma unroll
  for (int m = 32; m >= 1; m >>= 1) v += __shfl_xor(v, m, 64);
  return v;
}

// ---- edge_index dtype probe: int64 vs int32 (parallel) -------------------
__global__ void k_detect(const void* ei, int* flag) {
  __shared__ int sbad[4];
  int t = threadIdx.x;
  const i64* p = (const i64*)ei;
  i64 v = p[t];
  int bad = (v < 0 || v >= NN) ? 1 : 0;
  unsigned long long b = __ballot(bad);
  if ((t & 63) == 0) sbad[t >> 6] = (b != 0ULL);
  __syncthreads();
  if (t == 0) *flag = !(sbad[0] | sbad[1] | sbad[2] | sbad[3]);
}

static __device__ __forceinline__ int edge_at(const void* ei, int is64, int idx) {
  return is64 ? (int)((const i64*)ei)[idx] : ((const int*)ei)[idx];
}

// ---- CSR build (by destination) ------------------------------------------
__global__ void k_zero(int* deg, int* cur) {
  int i = blockIdx.x * blockDim.x + threadIdx.x;
  if (i < NN) { deg[i] = 0; cur[i] = 0; }
}

__global__ void k_count(const void* ei, const int* flag, int* deg) {
  int e = blockIdx.x * blockDim.x + threadIdx.x;
  if (e >= EE) return;
  int is64 = *flag;
  atomicAdd(&deg[edge_at(ei, is64, EE + e)], 1);
}

__global__ void k_dinv(const int* deg, float* dinv) {
  int i = blockIdx.x * blockDim.x + threadIdx.x;
  if (i < NN) dinv[i] = rsqrtf((float)(deg[i] + 1));  // +1 = self loop
}

__global__ void k_scan1(const int* deg, int* rowp, int* bsums) {
  __shared__ int sh[256];
  int t = threadIdx.x;
  int base = blockIdx.x * 1024 + t * 4;
  int v[4]; int s = 0;
#pragma unroll
  for (int j = 0; j < 4; ++j) { int idx = base + j; int x = (idx < NN) ? deg[idx] : 0; v[j] = x; s += x; }
  sh[t] = s; __syncthreads();
  for (int off = 1; off < 256; off <<= 1) {
    int x = (t >= off) ? sh[t - off] : 0;
    __syncthreads();
    sh[t] += x;
    __syncthreads();
  }
  if (t == 255) bsums[blockIdx.x] = sh[255];
  int run = sh[t] - s;
#pragma unroll
  for (int j = 0; j < 4; ++j) { int idx = base + j; if (idx < NN) rowp[idx] = run; run += v[j]; }
}

__global__ void k_scan2(int* bsums, int* rowp, int nb) {
  int lane = threadIdx.x & 63;
  int v = (lane < nb) ? bsums[lane] : 0;
  int x = v;
#pragma unroll
  for (int off = 1; off < 64; off <<= 1) {
    int y = __shfl_up(x, off, 64);
    if (lane >= off) x += y;
  }
  if (lane < nb) bsums[lane] = x - v;   // exclusive
  if (lane == 63) rowp[NN] = x;         // total == EE
}

__global__ void k_scan3(int* rowp, const int* bsums) {
  int i = blockIdx.x * blockDim.x + threadIdx.x;
  if (i < NN) rowp[i] += bsums[i >> 10];
}

__global__ void k_fill(const void* ei, const int* flag, const int* rowp, int* cur, int* csr) {
  int e = blockIdx.x * blockDim.x + threadIdx.x;
  if (e >= EE) return;
  int is64 = *flag;
  int s = edge_at(ei, is64, e);
  int d = edge_at(ei, is64, EE + e);
  int pos = rowp[d] + atomicAdd(&cur[d], 1);
  csr[pos] = s;
}

// ---- dense GEMM: Y[n][OC] = X[n][K] @ W[K][OC]; 2x2 register blocking ----
template <int K, int OC, int ROWS>
__global__ void k_gemm(const float* __restrict__ X, const float* __restrict__ W,
                       float* __restrict__ Y, int n) {
  __shared__ __align__(16) float Wl[K * OC];
  int t = threadIdx.x;
  for (int i = t; i < K * OC / 4; i += 256)
    ((float4*)Wl)[i] = ((const float4*)W)[i];
  __syncthreads();

  const int CP = OC / 2;       // col pairs
  const int RP = 256 / CP;     // thread row groups
  int tx = t % CP, ty = t / CP;
  int blockRow = blockIdx.x * ROWS;

  for (int rp = 0; rp < ROWS; rp += RP * 2) {
    int r0 = blockRow + rp + ty * 2;
    if (r0 >= n) break;
    int r1 = r0 + 1;
    bool has1 = (r1 < n);
    const float* x0p = X + (size_t)r0 * K;
    const float* x1p = X + (size_t)(has1 ? r1 : r0) * K;
    float a00 = 0.f, a01 = 0.f, a10 = 0.f, a11 = 0.f;
#pragma unroll 8
    for (int k = 0; k < K; ++k) {
      float2 w2 = ((const float2*)Wl)[k * CP + tx];
      float x0 = x0p[k], x1 = x1p[k];
      a00 += x0 * w2.x; a01 += x0 * w2.y;
      a10 += x1 * w2.x; a11 += x1 * w2.y;
    }
    ((float2*)(Y + (size_t)r0 * OC))[tx] = make_float2(a00, a01);
    if (has1) ((float2*)(Y + (size_t)r1 * OC))[tx] = make_float2(a10, a11);
  }
}

// ---- GCN aggregation: wave/node, lane=feature, LDS edge stash ------------
__global__ void k_gcn(const float* __restrict__ g, const float* __restrict__ dinv,
                      const int* __restrict__ rowp, const int* __restrict__ csr,
                      const float* __restrict__ bias, float* __restrict__ out) {
  __shared__ int   s_src[4][CAP];
  __shared__ float s_w[4][CAP];
  int wid = (blockIdx.x * blockDim.x + threadIdx.x) >> 6;
  int w = (threadIdx.x >> 6) & 3;
  int lane = threadIdx.x & 63;
  if (wid >= NN) return;
  float di = dinv[wid];
  int beg = rowp[wid], cnt = rowp[wid + 1] - beg;

  for (int idx = lane; idx < cnt; idx += 64) {
    int s = csr[beg + idx];
    if (idx < CAP) { s_src[w][idx] = s; s_w[w][idx] = dinv[s]; }
  }

  float acc = g[(size_t)wid * 64 + lane] * di;  // self loop
#pragma unroll 4
  for (int idx = 0; idx < cnt; ++idx) {
    int s; float ws;
    if (idx < CAP) { s = s_src[w][idx]; ws = s_w[w][idx]; }
    else { s = csr[beg + idx]; ws = dinv[s]; }
    acc += g[(size_t)s * 64 + lane] * ws;
  }
  float v = acc * di + bias[lane];
  out[(size_t)wid * 64 + lane] = fmaxf(v, 0.f);
}

// ---- attention coefficients ----------------------------------------------
__global__ void k_att1(const float* __restrict__ hg, const float* __restrict__ aw_s,
                       const float* __restrict__ aw_d, float* __restrict__ a_s,
                       float* __restrict__ a_d) {
  int wid = (blockIdx.x * blockDim.x + threadIdx.x) >> 6;
  int lane = threadIdx.x & 63;
  if (wid >= NN) return;
  const float* h = hg + (size_t)wid * 128;
  float h0 = h[lane], h1 = h[lane + 64];
  float s0 = wave_sum64(h0 * aw_s[lane]);
  float s1 = wave_sum64(h1 * aw_s[lane + 64]);
  float d0 = wave_sum64(h0 * aw_d[lane]);
  float d1 = wave_sum64(h1 * aw_d[lane + 64]);
  if (lane == 0) {
    a_s[wid * 2] = s0; a_s[wid * 2 + 1] = s1;
    a_d[wid * 2] = d0; a_d[wid * 2 + 1] = d1;
  }
}

__global__ void k_att2(const float* __restrict__ hg, const float* __restrict__ aw_s,
                       const float* __restrict__ aw_d, float* __restrict__ a_s,
                       float* __restrict__ a_d) {
  int wid = (blockIdx.x * blockDim.x + threadIdx.x) >> 6;
  int lane = threadIdx.x & 63;
  if (wid >= NN) return;
  float h0 = hg[(size_t)wid * 64 + lane];
  float s = h0 * aw_s[lane];
  float d = h0 * aw_d[lane];
#pragma unroll
  for (int m = 16; m >= 1; m >>= 1) { s += __shfl_xor(s, m, 64); d += __shfl_xor(d, m, 64); }
  if ((lane & 31) == 0) {
    a_s[wid * 2 + (lane >> 5)] = s;
    a_d[wid * 2 + (lane >> 5)] = d;
  }
}

// ---- GAT layer 1: wave per (node, head), LDS stash of src + exp ----------
__global__ void k_gat1(const float* __restrict__ hg, const float* __restrict__ a_s,
                       const float* __restrict__ a_d, const int* __restrict__ rowp,
                       const int* __restrict__ csr, const float* __restrict__ bias,
                       float* __restrict__ out) {
  __shared__ int   s_src[4][CAP];
  __shared__ float s_ex[4][CAP];
  int gwid = (blockIdx.x * blockDim.x + threadIdx.x) >> 6;
  int w = (threadIdx.x >> 6) & 3;
  int lane = threadIdx.x & 63;
  if (gwid >= NN * 2) return;
  int node = gwid >> 1, h = gwid & 1;

  int beg = rowp[node], cnt = rowp[node + 1] - beg;
  float adh = a_d[node * 2 + h];

  // phase 1: stash src + e, local max
  float m = -1e30f;
  for (int idx = lane; idx < cnt + 1; idx += 64) {
    int s = (idx < cnt) ? csr[beg + idx] : node;
    float e = a_s[s * 2 + h] + adh;
    e = e > 0.f ? e : NEG * e;
    if (idx < CAP) { s_src[w][idx] = s; s_ex[w][idx] = e; }
    m = fmaxf(m, e);
  }
  m = wave_max64(m);

  // phase 2: ex = exp(e-m), stash, sum
  float sum = 0.f;
  for (int idx = lane; idx < cnt + 1; idx += 64) {
    float e;
    if (idx < CAP) e = s_ex[w][idx];
    else {
      int s = (idx < cnt) ? csr[beg + idx] : node;
      e = a_s[s * 2 + h] + adh;
      e = e > 0.f ? e : NEG * e;
    }
    float ex = __expf(e - m);
    if (idx < CAP) s_ex[w][idx] = ex;
    sum += ex;
  }
  sum = wave_sum64(sum);
  float inv = 1.f / sum;

  // phase 3: serial aggregation over edges
  const float* hb = hg + h * 64 + lane;
  float acc = 0.f;
  int tot = cnt + 1;
#pragma unroll 4
  for (int idx = 0; idx < tot; ++idx) {
    int s; float a;
    if (idx < CAP) { s = s_src[w][idx]; a = s_ex[w][idx]; }
    else {
      s = (idx < cnt) ? csr[beg + idx] : node;
      float e = a_s[s * 2 + h] + adh;
      e = e > 0.f ? e : NEG * e;
      a = __expf(e - m);
    }
    acc += hb[(size_t)s * 128] * (a * inv);
  }
  float v = acc + bias[h * 64 + lane];
  out[(size_t)node * 128 + h * 64 + lane] = fmaxf(v, 0.f);
}

// ---- GAT layer 2 (H=2,C=32, head-mean) + log_softmax, LDS stash ----------
__global__ void k_gat2(const float* __restrict__ hg, const float* __restrict__ a_s,
                       const float* __restrict__ a_d, const int* __restrict__ rowp,
                       const int* __restrict__ csr, const float* __restrict__ bias,
                       float* __restrict__ out) {
  __shared__ int   s_src[4][CAP];
  __shared__ float s_e0[4][CAP];
  __shared__ float s_e1[4][CAP];
  int wid = (blockIdx.x * blockDim.x + threadIdx.x) >> 6;
  int w = (threadIdx.x >> 6) & 3;
  int lane = threadIdx.x & 63;
  if (wid >= NN) return;
  int hh = lane >> 5, c = lane & 31;
  int beg = rowp[wid], cnt = rowp[wid + 1] - beg;
  float ad0 = a_d[wid * 2], ad1 = a_d[wid * 2 + 1];

  // phase 1
  float m0 = -1e30f, m1 = -1e30f;
  for (int idx = lane; idx < cnt + 1; idx += 64) {
    int s = (idx < cnt) ? csr[beg + idx] : wid;
    float e0 = a_s[s * 2] + ad0, e1 = a_s[s * 2 + 1] + ad1;
    e0 = e0 > 0.f ? e0 : NEG * e0;
    e1 = e1 > 0.f ? e1 : NEG * e1;
    if (idx < CAP) { s_src[w][idx] = s; s_e0[w][idx] = e0; s_e1[w][idx] = e1; }
    m0 = fmaxf(m0, e0); m1 = fmaxf(m1, e1);
  }
  m0 = wave_max64(m0); m1 = wave_max64(m1);

  // phase 2
  float s0 = 0.f, s1 = 0.f;
  for (int idx = lane; idx < cnt + 1; idx += 64) {
    float e0, e1;
    if (idx < CAP) { e0 = s_e0[w][idx]; e1 = s_e1[w][idx]; }
    else {
      int s = (idx < cnt) ? csr[beg + idx] : wid;
      e0 = a_s[s * 2] + ad0; e1 = a_s[s * 2 + 1] + ad1;
      e0 = e0 > 0.f ? e0 : NEG * e0;
      e1 = e1 > 0.f ? e1 : NEG * e1;
    }
    float x0 = __expf(e0 - m0), x1 = __expf(e1 - m1);
    if (idx < CAP) { s_e0[w][idx] = x0; s_e1[w][idx] = x1; }
    s0 += x0; s1 += x1;
  }
  s0 = wave_sum64(s0); s1 = wave_sum64(s1);
  float mh = hh ? m1 : m0;
  float invh = 1.f / (hh ? s1 : s0);
  float adh = hh ? ad1 : ad0;

  // phase 3
  float acc = 0.f;
  int tot = cnt + 1;
#pragma unroll 4
  for (int idx = 0; idx < tot; ++idx) {
    int s; float a;
    if (idx < CAP) {
      s = s_src[w][idx];
      a = hh ? s_e1[w][idx] : s_e0[w][idx];
    } else {
      s = (idx < cnt) ? csr[beg + idx] : wid;
      float e = a_s[s * 2 + hh] + adh;
      e = e > 0.f ? e : NEG * e;
      a = __expf(e - mh);
    }
    acc += hg[(size_t)s * 64 + lane] * (a * invh);
  }
  float v = 0.5f * (acc + __shfl_xor(acc, 32, 64)) + bias[c];
  float mx = v;
#pragma unroll
  for (int m = 16; m >= 1; m >>= 1) mx = fmaxf(mx, __shfl_xor(mx, m, 64));
  float se = __expf(v - mx);
#pragma unroll
  for (int m = 16; m >= 1; m >>= 1) se += __shfl_xor(se, m, 64);
  float o = v - mx - __logf(se);
  if (lane < 32) out[(size_t)wid * 32 + c] = o;
}

// --------------------------------------------------------------------------
extern "C" void kernel_launch(void* const* d_in, const int* in_sizes, int n_in,
                              void* d_out, int out_size, void* d_ws, size_t ws_size,
                              hipStream_t stream) {
  (void)in_sizes; (void)n_in; (void)out_size; (void)ws_size;
  const float* x   = (const float*)d_in[0];
  const void*  ei  = d_in[1];
  const float* W1  = (const float*)d_in[2];
  const float* b1  = (const float*)d_in[3];
  const float* W2  = (const float*)d_in[4];
  const float* b2  = (const float*)d_in[5];
  const float* Wg1 = (const float*)d_in[6];
  const float* as1 = (const float*)d_in[7];
  const float* ad1 = (const float*)d_in[8];
  const float* bg1 = (const float*)d_in[9];
  const float* Wg2 = (const float*)d_in[10];
  const float* as2 = (const float*)d_in[11];
  const float* ad2 = (const float*)d_in[12];
  const float* bg2 = (const float*)d_in[13];
  float* out = (float*)d_out;

  char* w = (char*)d_ws;
  auto alloc = [&](size_t bytes) { char* p = w; w += (bytes + 255) & ~(size_t)255; return p; };
  float* B1   = (float*)alloc((size_t)NN * 128 * 4);
  float* B2   = (float*)alloc((size_t)NN * 128 * 4);
  float* dinv = (float*)alloc((size_t)NN * 4);
  float* asb  = (float*)alloc((size_t)NN * 2 * 4);
  float* adb  = (float*)alloc((size_t)NN * 2 * 4);
  int* deg    = (int*)alloc((size_t)NN * 4);
  int* rowp   = (int*)alloc((size_t)(NN + 1) * 4);
  int* cur    = (int*)alloc((size_t)NN * 4);
  int* csr    = (int*)alloc((size_t)EE * 4);
  int* bsums  = (int*)alloc(64 * 4);
  int* flag   = (int*)alloc(16);

  const int TB = 256;
  int gN = (NN + TB - 1) / TB;
  int gE = (EE + TB - 1) / TB;
  int gW = (NN + 3) / 4;          // wave per node
  int gW2 = (2 * NN + 3) / 4;     // wave per (node, head)
  int nScan = (NN + 1023) / 1024; // 49

  k_detect<<<1, 256, 0, stream>>>(ei, flag);
  k_zero<<<gN, TB, 0, stream>>>(deg, cur);
  k_count<<<gE, TB, 0, stream>>>(ei, flag, deg);
  k_dinv<<<gN, TB, 0, stream>>>(deg, dinv);
  k_scan1<<<nScan, TB, 0, stream>>>(deg, rowp, bsums);
  k_scan2<<<1, 64, 0, stream>>>(bsums, rowp, nScan);
  k_scan3<<<gN, TB, 0, stream>>>(rowp, bsums);
  k_fill<<<gE, TB, 0, stream>>>(ei, flag, rowp, cur, csr);

  // GCN 1
  k_gemm<128, 64, 64><<<(NN + 63) / 64, TB, 0, stream>>>(x, W1, B1, NN);
  k_gcn<<<gW, TB, 0, stream>>>(B1, dinv, rowp, csr, b1, B2);
  // GCN 2
  k_gemm<64, 64, 64><<<(NN + 63) / 64, TB, 0, stream>>>(B2, W2, B1, NN);
  k_gcn<<<gW, TB, 0, stream>>>(B1, dinv, rowp, csr, b2, B2);
  // GAT 1 (concat, relu)
  k_gemm<64, 128, 64><<<(NN + 63) / 64, TB, 0, stream>>>(B2, Wg1, B1, NN);
  k_att1<<<gW, TB, 0, stream>>>(B1, as1, ad1, asb, adb);
  k_gat1<<<gW2, TB, 0, stream>>>(B1, asb, adb, rowp, csr, bg1, B2);
  // GAT 2 (head mean) + log_softmax
  k_gemm<128, 64, 64><<<(NN + 63) / 64, TB, 0, stream>>>(B2, Wg2, B1, NN);
  k_att2<<<gW, TB, 0, stream>>>(B1, as2, ad2, asb, adb);
  k_gat2<<<gW, TB, 0, stream>>>(B1, asb, adb, rowp, csr, bg2, out);
}

// Round 3
// 405.432 us; speedup vs baseline: 1.8205x; 1.1293x over previous
//
#include <hip/hip_runtime.h>

#define NN 50000
#define EE 800000
#define NEG 0.2f
#define CAP 128   // per-wave LDS edge stash (deg ~Poisson(16), max ~45; tail path kept for safety)

typedef long long i64;

static __device__ __forceinline__ float wave_max64(float v) {
#pragma unroll
  for (int m = 32; m >= 1; m >>= 1) v = fmaxf(v, __shfl_xor(v, m, 64));
  return v;
}
static __device__ __forceinline__ float wave_sum64(float v) {
#pragma unroll
  for (int m = 32; m >= 1; m >>= 1) v += __shfl_xor(v, m, 64);
  return v;
}

// bf16 helpers (manual, round-to-nearest-even)
static __device__ __forceinline__ unsigned short f2bf(float f) {
  unsigned u = __float_as_uint(f);
  u += 0x7FFFu + ((u >> 16) & 1u);
  return (unsigned short)(u >> 16);
}
static __device__ __forceinline__ float bf2f(unsigned short b) {
  return __uint_as_float(((unsigned)b) << 16);
}

// ---- edge_index dtype probe: int64 vs int32 (parallel) -------------------
__global__ void k_detect(const void* ei, int* flag) {
  __shared__ int sbad[4];
  int t = threadIdx.x;
  const i64* p = (const i64*)ei;
  i64 v = p[t];
  int bad = (v < 0 || v >= NN) ? 1 : 0;
  unsigned long long b = __ballot(bad);
  if ((t & 63) == 0) sbad[t >> 6] = (b != 0ULL);
  __syncthreads();
  if (t == 0) *flag = !(sbad[0] | sbad[1] | sbad[2] | sbad[3]);
}

static __device__ __forceinline__ int edge_at(const void* ei, int is64, int idx) {
  return is64 ? (int)((const i64*)ei)[idx] : ((const int*)ei)[idx];
}

// ---- CSR build (by destination) ------------------------------------------
__global__ void k_zero(int* deg, int* cur) {
  int i = blockIdx.x * blockDim.x + threadIdx.x;
  if (i < NN) { deg[i] = 0; cur[i] = 0; }
}

__global__ void k_count(const void* ei, const int* flag, int* deg) {
  int e = blockIdx.x * blockDim.x + threadIdx.x;
  if (e >= EE) return;
  int is64 = *flag;
  atomicAdd(&deg[edge_at(ei, is64, EE + e)], 1);
}

__global__ void k_dinv(const int* deg, float* dinv) {
  int i = blockIdx.x * blockDim.x + threadIdx.x;
  if (i < NN) dinv[i] = rsqrtf((float)(deg[i] + 1));  // +1 = self loop
}

__global__ void k_scan1(const int* deg, int* rowp, int* bsums) {
  __shared__ int sh[256];
  int t = threadIdx.x;
  int base = blockIdx.x * 1024 + t * 4;
  int v[4]; int s = 0;
#pragma unroll
  for (int j = 0; j < 4; ++j) { int idx = base + j; int x = (idx < NN) ? deg[idx] : 0; v[j] = x; s += x; }
  sh[t] = s; __syncthreads();
  for (int off = 1; off < 256; off <<= 1) {
    int x = (t >= off) ? sh[t - off] : 0;
    __syncthreads();
    sh[t] += x;
    __syncthreads();
  }
  if (t == 255) bsums[blockIdx.x] = sh[255];
  int run = sh[t] - s;
#pragma unroll
  for (int j = 0; j < 4; ++j) { int idx = base + j; if (idx < NN) rowp[idx] = run; run += v[j]; }
}

__global__ void k_scan2(int* bsums, int* rowp, int nb) {
  int lane = threadIdx.x & 63;
  int v = (lane < nb) ? bsums[lane] : 0;
  int x = v;
#pragma unroll
  for (int off = 1; off < 64; off <<= 1) {
    int y = __shfl_up(x, off, 64);
    if (lane >= off) x += y;
  }
  if (lane < nb) bsums[lane] = x - v;
  if (lane == 63) rowp[NN] = x;
}

__global__ void k_scan3(int* rowp, const int* bsums) {
  int i = blockIdx.x * blockDim.x + threadIdx.x;
  if (i < NN) rowp[i] += bsums[i >> 10];
}

__global__ void k_fill(const void* ei, const int* flag, const int* rowp, int* cur, int* csr) {
  int e = blockIdx.x * blockDim.x + threadIdx.x;
  if (e >= EE) return;
  int is64 = *flag;
  int s = edge_at(ei, is64, e);
  int d = edge_at(ei, is64, EE + e);
  int pos = rowp[d] + atomicAdd(&cur[d], 1);
  csr[pos] = s;
}

// ---- dense GEMM: Y(bf16)[n][OC] = X(f32)[n][K] @ W[K][OC]; 2x2 blocking --
template <int K, int OC, int ROWS>
__global__ void k_gemm(const float* __restrict__ X, const float* __restrict__ W,
                       unsigned short* __restrict__ Y, int n) {
  __shared__ __align__(16) float Wl[K * OC];
  int t = threadIdx.x;
  for (int i = t; i < K * OC / 4; i += 256)
    ((float4*)Wl)[i] = ((const float4*)W)[i];
  __syncthreads();

  const int CP = OC / 2;
  const int RP = 256 / CP;
  int tx = t % CP, ty = t / CP;
  int blockRow = blockIdx.x * ROWS;
  const float2* Wl2 = (const float2*)Wl;

  for (int rp = 0; rp < ROWS; rp += RP * 2) {
    int r0 = blockRow + rp + ty * 2;
    if (r0 >= n) break;
    int r1 = r0 + 1;
    bool has1 = (r1 < n);
    const float4* x0q = (const float4*)(X + (size_t)r0 * K);
    const float4* x1q = (const float4*)(X + (size_t)(has1 ? r1 : r0) * K);
    float a00 = 0.f, a01 = 0.f, a10 = 0.f, a11 = 0.f;
#pragma unroll 4
    for (int k4 = 0; k4 < K / 4; ++k4) {
      float4 xa = x0q[k4];
      float4 xb = x1q[k4];
      const float* pa = &xa.x;
      const float* pb = &xb.x;
#pragma unroll
      for (int j = 0; j < 4; ++j) {
        float2 w2 = Wl2[(k4 * 4 + j) * CP + tx];
        a00 += pa[j] * w2.x; a01 += pa[j] * w2.y;
        a10 += pb[j] * w2.x; a11 += pb[j] * w2.y;
      }
    }
    ((ushort2*)(Y + (size_t)r0 * OC))[tx] = make_ushort2(f2bf(a00), f2bf(a01));
    if (has1) ((ushort2*)(Y + (size_t)r1 * OC))[tx] = make_ushort2(f2bf(a10), f2bf(a11));
  }
}

// ---- GCN aggregation: wave/node, lane=feature(64), bf16 gather -----------
__global__ void k_gcn(const unsigned short* __restrict__ g, const float* __restrict__ dinv,
                      const int* __restrict__ rowp, const int* __restrict__ csr,
                      const float* __restrict__ bias, float* __restrict__ out) {
  __shared__ float2 st[4][CAP];
  int wid = (blockIdx.x * blockDim.x + threadIdx.x) >> 6;
  int w = (threadIdx.x >> 6) & 3;
  int lane = threadIdx.x & 63;
  if (wid >= NN) return;
  float di = dinv[wid];
  int beg = rowp[wid], cnt = rowp[wid + 1] - beg;
  int c1 = min(cnt, CAP);

  for (int idx = lane; idx < c1; idx += 64) {
    int s = csr[beg + idx];
    st[w][idx] = make_float2(__int_as_float(s), dinv[s]);
  }

  float acc = bf2f(g[(size_t)wid * 64 + lane]) * di;  // self loop
#pragma unroll 4
  for (int idx = 0; idx < c1; ++idx) {
    float2 p = st[w][idx];
    int s = __float_as_int(p.x);
    acc += bf2f(g[(size_t)s * 64 + lane]) * p.y;
  }
  for (int idx = CAP; idx < cnt; ++idx) {  // essentially never
    int s = csr[beg + idx];
    acc += bf2f(g[(size_t)s * 64 + lane]) * dinv[s];
  }
  float v = acc * di + bias[lane];
  out[(size_t)wid * 64 + lane] = fmaxf(v, 0.f);
}

// ---- attention coefficients (bf16 h) -------------------------------------
__global__ void k_att1(const unsigned short* __restrict__ hg, const float* __restrict__ aw_s,
                       const float* __restrict__ aw_d, float* __restrict__ a_s,
                       float* __restrict__ a_d) {
  int wid = (blockIdx.x * blockDim.x + threadIdx.x) >> 6;
  int lane = threadIdx.x & 63;
  if (wid >= NN) return;
  const unsigned short* h = hg + (size_t)wid * 128;
  float h0 = bf2f(h[lane]), h1 = bf2f(h[lane + 64]);
  float s0 = wave_sum64(h0 * aw_s[lane]);
  float s1 = wave_sum64(h1 * aw_s[lane + 64]);
  float d0 = wave_sum64(h0 * aw_d[lane]);
  float d1 = wave_sum64(h1 * aw_d[lane + 64]);
  if (lane == 0) {
    a_s[wid * 2] = s0; a_s[wid * 2 + 1] = s1;
    a_d[wid * 2] = d0; a_d[wid * 2 + 1] = d1;
  }
}

__global__ void k_att2(const unsigned short* __restrict__ hg, const float* __restrict__ aw_s,
                       const float* __restrict__ aw_d, float* __restrict__ a_s,
                       float* __restrict__ a_d) {
  int wid = (blockIdx.x * blockDim.x + threadIdx.x) >> 6;
  int lane = threadIdx.x & 63;
  if (wid >= NN) return;
  float h0 = bf2f(hg[(size_t)wid * 64 + lane]);
  float s = h0 * aw_s[lane];
  float d = h0 * aw_d[lane];
#pragma unroll
  for (int m = 16; m >= 1; m >>= 1) { s += __shfl_xor(s, m, 64); d += __shfl_xor(d, m, 64); }
  if ((lane & 31) == 0) {
    a_s[wid * 2 + (lane >> 5)] = s;
    a_d[wid * 2 + (lane >> 5)] = d;
  }
}

// ---- GAT layer 1: wave per (node, head), bf16 gather ---------------------
__global__ void k_gat1(const unsigned short* __restrict__ hg, const float* __restrict__ a_s,
                       const float* __restrict__ a_d, const int* __restrict__ rowp,
                       const int* __restrict__ csr, const float* __restrict__ bias,
                       float* __restrict__ out) {
  __shared__ float2 st[4][CAP];  // (src bits, e then ex)
  int gwid = (blockIdx.x * blockDim.x + threadIdx.x) >> 6;
  int w = (threadIdx.x >> 6) & 3;
  int lane = threadIdx.x & 63;
  if (gwid >= NN * 2) return;
  int node = gwid >> 1, h = gwid & 1;

  int beg = rowp[node], cnt = rowp[node + 1] - beg;
  int tot = cnt + 1;
  int c1 = min(tot, CAP);
  float adh = a_d[node * 2 + h];

  // phase 1: stash (src, e), max
  float m = -1e30f;
  for (int idx = lane; idx < c1; idx += 64) {
    int s = (idx < cnt) ? csr[beg + idx] : node;
    float e = a_s[s * 2 + h] + adh;
    e = e > 0.f ? e : NEG * e;
    st[w][idx] = make_float2(__int_as_float(s), e);
    m = fmaxf(m, e);
  }
  for (int idx = CAP + lane; idx < tot; idx += 64) {  // essentially never
    int s = (idx < cnt) ? csr[beg + idx] : node;
    float e = a_s[s * 2 + h] + adh;
    e = e > 0.f ? e : NEG * e;
    m = fmaxf(m, e);
  }
  m = wave_max64(m);

  // phase 2: ex = exp(e-m), stash back, sum
  float sum = 0.f;
  for (int idx = lane; idx < c1; idx += 64) {
    float ex = __expf(st[w][idx].y - m);
    st[w][idx].y = ex;
    sum += ex;
  }
  for (int idx = CAP + lane; idx < tot; idx += 64) {
    int s = (idx < cnt) ? csr[beg + idx] : node;
    float e = a_s[s * 2 + h] + adh;
    e = e > 0.f ? e : NEG * e;
    sum += __expf(e - m);
  }
  sum = wave_sum64(sum);
  float inv = 1.f / sum;

  // phase 3: serial weighted gather; 1/sum folded out of the loop
  const unsigned short* hb = hg + h * 64 + lane;
  float acc = 0.f;
#pragma unroll 4
  for (int idx = 0; idx < c1; ++idx) {
    float2 p = st[w][idx];
    int s = __float_as_int(p.x);
    acc += bf2f(hb[(size_t)s * 128]) * p.y;
  }
  for (int idx = CAP; idx < tot; ++idx) {
    int s = (idx < cnt) ? csr[beg + idx] : node;
    float e = a_s[s * 2 + h] + adh;
    e = e > 0.f ? e : NEG * e;
    acc += bf2f(hb[(size_t)s * 128]) * __expf(e - m);
  }
  float v = acc * inv + bias[h * 64 + lane];
  out[(size_t)node * 128 + h * 64 + lane] = fmaxf(v, 0.f);
}

// ---- GAT layer 2 (H=2,C=32, head-mean) + log_softmax ---------------------
__global__ void k_gat2(const unsigned short* __restrict__ hg, const float* __restrict__ a_s,
                       const float* __restrict__ a_d, const int* __restrict__ rowp,
                       const int* __restrict__ csr, const float* __restrict__ bias,
                       float* __restrict__ out) {
  __shared__ float4 st[4][CAP];  // (src bits, e0/ex0, e1/ex1, pad)
  int wid = (blockIdx.x * blockDim.x + threadIdx.x) >> 6;
  int w = (threadIdx.x >> 6) & 3;
  int lane = threadIdx.x & 63;
  if (wid >= NN) return;
  int hh = lane >> 5, c = lane & 31;
  int beg = rowp[wid], cnt = rowp[wid + 1] - beg;
  int tot = cnt + 1;
  int c1 = min(tot, CAP);
  float ad0 = a_d[wid * 2], ad1 = a_d[wid * 2 + 1];

  float m0 = -1e30f, m1 = -1e30f;
  for (int idx = lane; idx < c1; idx += 64) {
    int s = (idx < cnt) ? csr[beg + idx] : wid;
    float e0 = a_s[s * 2] + ad0, e1 = a_s[s * 2 + 1] + ad1;
    e0 = e0 > 0.f ? e0 : NEG * e0;
    e1 = e1 > 0.f ? e1 : NEG * e1;
    st[w][idx] = make_float4(__int_as_float(s), e0, e1, 0.f);
    m0 = fmaxf(m0, e0); m1 = fmaxf(m1, e1);
  }
  for (int idx = CAP + lane; idx < tot; idx += 64) {
    int s = (idx < cnt) ? csr[beg + idx] : wid;
    float e0 = a_s[s * 2] + ad0, e1 = a_s[s * 2 + 1] + ad1;
    e0 = e0 > 0.f ? e0 : NEG * e0;
    e1 = e1 > 0.f ? e1 : NEG * e1;
    m0 = fmaxf(m0, e0); m1 = fmaxf(m1, e1);
  }
  m0 = wave_max64(m0); m1 = wave_max64(m1);

  float s0 = 0.f, s1 = 0.f;
  for (int idx = lane; idx < c1; idx += 64) {
    float4 p = st[w][idx];
    float x0 = __expf(p.y - m0), x1 = __expf(p.z - m1);
    st[w][idx] = make_float4(p.x, x0, x1, 0.f);
    s0 += x0; s1 += x1;
  }
  for (int idx = CAP + lane; idx < tot; idx += 64) {
    int s = (idx < cnt) ? csr[beg + idx] : wid;
    float e0 = a_s[s * 2] + ad0, e1 = a_s[s * 2 + 1] + ad1;
    e0 = e0 > 0.f ? e0 : NEG * e0;
    e1 = e1 > 0.f ? e1 : NEG * e1;
    s0 += __expf(e0 - m0); s1 += __expf(e1 - m1);
  }
  s0 = wave_sum64(s0); s1 = wave_sum64(s1);
  float invh = 1.f / (hh ? s1 : s0);
  float mh = hh ? m1 : m0;
  float adh = hh ? ad1 : ad0;

  float acc = 0.f;
#pragma unroll 4
  for (int idx = 0; idx < c1; ++idx) {
    float4 p = st[w][idx];
    int s = __float_as_int(p.x);
    float a = hh ? p.z : p.y;
    acc += bf2f(hg[(size_t)s * 64 + lane]) * a;
  }
  for (int idx = CAP; idx < tot; ++idx) {
    int s = (idx < cnt) ? csr[beg + idx] : wid;
    float e = a_s[s * 2 + hh] + adh;
    e = e > 0.f ? e : NEG * e;
    acc += bf2f(hg[(size_t)s * 64 + lane]) * __expf(e - mh);
  }
  float accs = acc * invh;
  float v = 0.5f * (accs + __shfl_xor(accs, 32, 64)) + bias[c];
  float mx = v;
#pragma unroll
  for (int m = 16; m >= 1; m >>= 1) mx = fmaxf(mx, __shfl_xor(mx, m, 64));
  float se = __expf(v - mx);
#pragma unroll
  for (int m = 16; m >= 1; m >>= 1) se += __shfl_xor(se, m, 64);
  float o = v - mx - __logf(se);
  if (lane < 32) out[(size_t)wid * 32 + c] = o;
}

// --------------------------------------------------------------------------
extern "C" void kernel_launch(void* const* d_in, const int* in_sizes, int n_in,
                              void* d_out, int out_size, void* d_ws, size_t ws_size,
                              hipStream_t stream) {
  (void)in_sizes; (void)n_in; (void)out_size; (void)ws_size;
  const float* x   = (const float*)d_in[0];
  const void*  ei  = d_in[1];
  const float* W1  = (const float*)d_in[2];
  const float* b1  = (const float*)d_in[3];
  const float* W2  = (const float*)d_in[4];
  const float* b2  = (const float*)d_in[5];
  const float* Wg1 = (const float*)d_in[6];
  const float* as1 = (const float*)d_in[7];
  const float* ad1 = (const float*)d_in[8];
  const float* bg1 = (const float*)d_in[9];
  const float* Wg2 = (const float*)d_in[10];
  const float* as2 = (const float*)d_in[11];
  const float* ad2 = (const float*)d_in[12];
  const float* bg2 = (const float*)d_in[13];
  float* out = (float*)d_out;

  char* w = (char*)d_ws;
  auto alloc = [&](size_t bytes) { char* p = w; w += (bytes + 255) & ~(size_t)255; return p; };
  unsigned short* Hb = (unsigned short*)alloc((size_t)NN * 128 * 2);  // bf16 gather table
  float* Hf   = (float*)alloc((size_t)NN * 128 * 4);                  // fp32 agg output
  float* dinv = (float*)alloc((size_t)NN * 4);
  float* asb  = (float*)alloc((size_t)NN * 2 * 4);
  float* adb  = (float*)alloc((size_t)NN * 2 * 4);
  int* deg    = (int*)alloc((size_t)NN * 4);
  int* rowp   = (int*)alloc((size_t)(NN + 1) * 4);
  int* cur    = (int*)alloc((size_t)NN * 4);
  int* csr    = (int*)alloc((size_t)EE * 4);
  int* bsums  = (int*)alloc(64 * 4);
  int* flag   = (int*)alloc(16);

  const int TB = 256;
  int gN = (NN + TB - 1) / TB;
  int gE = (EE + TB - 1) / TB;
  int gW = (NN + 3) / 4;
  int gW2 = (2 * NN + 3) / 4;
  int nScan = (NN + 1023) / 1024;

  k_detect<<<1, 256, 0, stream>>>(ei, flag);
  k_zero<<<gN, TB, 0, stream>>>(deg, cur);
  k_count<<<gE, TB, 0, stream>>>(ei, flag, deg);
  k_dinv<<<gN, TB, 0, stream>>>(deg, dinv);
  k_scan1<<<nScan, TB, 0, stream>>>(deg, rowp, bsums);
  k_scan2<<<1, 64, 0, stream>>>(bsums, rowp, nScan);
  k_scan3<<<gN, TB, 0, stream>>>(rowp, bsums);
  k_fill<<<gE, TB, 0, stream>>>(ei, flag, rowp, cur, csr);

  // GCN 1
  k_gemm<128, 64, 64><<<(NN + 63) / 64, TB, 0, stream>>>(x, W1, Hb, NN);
  k_gcn<<<gW, TB, 0, stream>>>(Hb, dinv, rowp, csr, b1, Hf);
  // GCN 2
  k_gemm<64, 64, 64><<<(NN + 63) / 64, TB, 0, stream>>>(Hf, W2, Hb, NN);
  k_gcn<<<gW, TB, 0, stream>>>(Hb, dinv, rowp, csr, b2, Hf);
  // GAT 1 (concat, relu)
  k_gemm<64, 128, 64><<<(NN + 63) / 64, TB, 0, stream>>>(Hf, Wg1, Hb, NN);
  k_att1<<<gW, TB, 0, stream>>>(Hb, as1, ad1, asb, adb);
  k_gat1<<<gW2, TB, 0, stream>>>(Hb, asb, adb, rowp, csr, bg1, Hf);
  // GAT 2 (head mean) + log_softmax
  k_gemm<128, 64, 64><<<(NN + 63) / 64, TB, 0, stream>>>(Hf, Wg2, Hb, NN);
  k_att2<<<gW, TB, 0, stream>>>(Hb, as2, ad2, asb, adb);
  k_gat2<<<gW, TB, 0, stream>>>(Hb, asb, adb, rowp, csr, bg2, out);
}